// Round 5
// baseline (300.739 us; speedup 1.0000x reference)
//
#include <hip/hip_runtime.h>

// ---------------------------------------------------------------------------
// FlexibleGraphSAGE: 3-layer SAGEConv (mean aggregation).
//   per layer: out = mean_agg(h) @ Wl^T + bl + h @ Wr^T   (+ReLU on layers 0,1)
// R17: R16 + per-node degree precompute (deg[]) to halve bucket_build:
//   - hist dispatch gains 196 spare blocks that zero deg[] (dispatch-ordered
//     before scatter's atomics; hist itself is underutilized at 178 blocks).
//   - scatter adds one global atomicAdd(&deg[dst],1) per edge (already
//     touching every edge; ~16/counter contention over 50000 counters).
//   - bucket_build drops its ENTIRE first bedge pass (3.2MB read + 800k LDS
//     atomics + barrier chain): reads deg[node] directly, keeps the identical
//     LDS exclusive scan + placement pass -> bit-identical CSR output.
// R16/R15: fused L1-finish/L2-dual GEMM (LDS hand-off, h2 never in HBM).
// R14: layer 0 = T-trick dual GEMM on f32 x co-scheduled inside CSR dispatches;
//   layer 1 fused (no R1 materialization); layer 2 T-trick (gather 128->64).
//   Gather kernels byte-identical to R10's proven quarter-wave structure
//   (R9/R10/R11: pinned at random-256B fabric ceiling; all <44us per rocprof).
// ---------------------------------------------------------------------------

#define D_H 128
#define NBUCKET 196          // ceil(50000/256) node buckets of 256
#define EPB 8192             // edges per histogram/scatter block
#define NBLK 98              // ceil(800000/8192)
#define NZBLK 196            // deg-zeroing blocks (50000/256)

typedef _Float16 half8  __attribute__((ext_vector_type(8)));
typedef _Float16 half4v __attribute__((ext_vector_type(4)));
typedef float    floatx4 __attribute__((ext_vector_type(4)));

// ---------------- CSR step 1 + weight conversion + deg zeroing --------------
__global__ __launch_bounds__(256) void hist_wconv_kernel(
        const int* __restrict__ dst, int* __restrict__ histo, int E,
        const float* __restrict__ w0, const float* __restrict__ w1,
        const float* __restrict__ w2, const float* __restrict__ w3,
        const float* __restrict__ w4, const float* __restrict__ w5,
        _Float16* __restrict__ o0, _Float16* __restrict__ o1,
        _Float16* __restrict__ o2, _Float16* __restrict__ o3,
        _Float16* __restrict__ o4, _Float16* __restrict__ o5,
        int* __restrict__ deg, int n) {
    if (blockIdx.x < NBLK) {
        __shared__ int h[NBUCKET];
        for (int i = threadIdx.x; i < NBUCKET; i += 256) h[i] = 0;
        __syncthreads();
        int base = blockIdx.x * EPB;
        int end = min(base + EPB, E);
        for (int i = base + threadIdx.x; i < end; i += 256)
            atomicAdd(&h[dst[i] >> 8], 1);
        __syncthreads();
        for (int i = threadIdx.x; i < NBUCKET; i += 256)
            histo[blockIdx.x * NBUCKET + i] = h[i];
        return;
    }
    if (blockIdx.x >= NBLK + 80) {           // deg zeroing (before scatter's atomics)
        int node = (blockIdx.x - NBLK - 80) * 256 + threadIdx.x;
        if (node < n) deg[node] = 0;
        return;
    }
    int k = (blockIdx.x - NBLK) * 256 + threadIdx.x;
    const float* in; _Float16* out; int j;
    if      (k <  4096) { in = w0; out = o0; j = k; }
    else if (k <  8192) { in = w1; out = o1; j = k - 4096; }
    else if (k < 12288) { in = w2; out = o2; j = k - 8192; }
    else if (k < 16384) { in = w3; out = o3; j = k - 12288; }
    else if (k < 18432) { in = w4; out = o4; j = k - 16384; }
    else                { in = w5; out = o5; j = k - 18432; }
    float4 v = ((const float4*)in)[j];
    half4v o = { (_Float16)v.x, (_Float16)v.y, (_Float16)v.z, (_Float16)v.w };
    ((half4v*)out)[j] = o;
}

// ---------------- dual GEMM tile (64 rows, T-pass or R-pass) ----------------
// gtile space: [0, ntile) = T-pass (out = A@Wl^T), [ntile, 2*ntile) = R-pass
// (out = A@Wr^T + bias). Two-pass keeps acc at 64 VGPRs; second x read is LLC.
__device__ __forceinline__ void dual_tile_f32(
        const float* __restrict__ Af,
        const _Float16* __restrict__ Wl, const _Float16* __restrict__ Wr,
        const float* __restrict__ bias,
        _Float16* __restrict__ T, _Float16* __restrict__ R,
        int N, int g) {
    const int ntile = (N + 63) >> 6;
    if (g >= 2 * ntile) return;
    const bool rpass = g >= ntile;
    const _Float16* __restrict__ W = rpass ? Wr : Wl;
    _Float16* __restrict__ O = rpass ? R : T;
    const int tile = rpass ? g - ntile : g;
    const int lt   = threadIdx.x & 127;
    const int wave = lt >> 6;
    const int lane = lt & 63;
    const int r16  = lane & 15;
    const int quad = lane >> 4;
    const int base = tile * 64 + wave * 32;
    const int koff = quad * 8;
    const int row0 = min(base + r16,      N - 1);   // clamp: x has exactly N rows
    const int row1 = min(base + 16 + r16, N - 1);

    floatx4 acc[2][8];
    #pragma unroll
    for (int s = 0; s < 2; ++s)
        #pragma unroll
        for (int j = 0; j < 8; ++j)
            acc[s][j] = (floatx4){0.f, 0.f, 0.f, 0.f};

    #pragma unroll
    for (int k0 = 0; k0 < 128; k0 += 32) {
        float4 p0 = *(const float4*)&Af[(size_t)row0 * 128 + k0 + koff];
        float4 p1 = *(const float4*)&Af[(size_t)row0 * 128 + k0 + koff + 4];
        float4 q0 = *(const float4*)&Af[(size_t)row1 * 128 + k0 + koff];
        float4 q1 = *(const float4*)&Af[(size_t)row1 * 128 + k0 + koff + 4];
        half8 a0 = (half8){ (_Float16)p0.x, (_Float16)p0.y, (_Float16)p0.z, (_Float16)p0.w,
                            (_Float16)p1.x, (_Float16)p1.y, (_Float16)p1.z, (_Float16)p1.w };
        half8 a1 = (half8){ (_Float16)q0.x, (_Float16)q0.y, (_Float16)q0.z, (_Float16)q0.w,
                            (_Float16)q1.x, (_Float16)q1.y, (_Float16)q1.z, (_Float16)q1.w };
        #pragma unroll
        for (int j = 0; j < 8; ++j) {
            half8 b = *(const half8*)&W[(size_t)(j * 16 + r16) * 128 + k0 + koff];
            acc[0][j] = __builtin_amdgcn_mfma_f32_16x16x32_f16(a0, b, acc[0][j], 0, 0, 0);
            acc[1][j] = __builtin_amdgcn_mfma_f32_16x16x32_f16(a1, b, acc[1][j], 0, 0, 0);
        }
    }

    #pragma unroll
    for (int s = 0; s < 2; ++s)
        #pragma unroll
        for (int i = 0; i < 4; ++i) {
            int r = base + s * 16 + quad * 4 + i;
            if (r >= N) continue;
            #pragma unroll
            for (int j = 0; j < 8; ++j) {
                int c = j * 16 + r16;
                float v = acc[s][j][i];
                if (rpass) v += bias[c];
                O[(size_t)r * 128 + c] = (_Float16)v;
            }
        }
}

// ---------------- CSR step 2 (scan) + layer-0 GEMM chunk --------------------
__global__ __launch_bounds__(256) void scan_gemm_kernel(
        const int* __restrict__ histo, int* __restrict__ offs,
        int* __restrict__ boff, int* __restrict__ row_ptr, int n,
        const float* __restrict__ x, const _Float16* __restrict__ Wl,
        const _Float16* __restrict__ Wr, const float* __restrict__ bias,
        _Float16* __restrict__ T, _Float16* __restrict__ R, int gofs) {
    if (blockIdx.x == 0) {
        __shared__ int s[256];
        int t = threadIdx.x;
        int sum = 0;
        if (t < NBUCKET) {
            for (int b = 0; b < NBLK; ++b) {
                offs[b * NBUCKET + t] = sum;
                sum += histo[b * NBUCKET + t];
            }
        }
        s[t] = (t < NBUCKET) ? sum : 0;
        int tot = s[t];
        __syncthreads();
        for (int off = 1; off < 256; off <<= 1) {
            int tmp = (t >= off) ? s[t - off] : 0;
            __syncthreads();
            s[t] += tmp;
            __syncthreads();
        }
        int base = s[t] - tot;
        if (t < NBUCKET) boff[t] = base;
        if (t == 255) { boff[NBUCKET] = s[255]; row_ptr[n] = s[255]; }
        __syncthreads();
        if (t < NBUCKET)
            for (int b = 0; b < NBLK; ++b)
                offs[b * NBUCKET + t] += base;
        return;
    }
    int g = (blockIdx.x - 1) * 2 + (threadIdx.x >> 7) + gofs;
    dual_tile_f32(x, Wl, Wr, bias, T, R, n, g);
}

// ------- CSR step 3 (scatter + per-node degree) + layer-0 GEMM chunk --------
__global__ __launch_bounds__(256) void scatter_gemm_kernel(
        const int* __restrict__ src, const int* __restrict__ dst,
        const int* __restrict__ offs, unsigned int* __restrict__ bedge,
        int* __restrict__ deg, int E,
        const float* __restrict__ x, const _Float16* __restrict__ Wl,
        const _Float16* __restrict__ Wr, const float* __restrict__ bias,
        _Float16* __restrict__ T, _Float16* __restrict__ R, int N, int gofs) {
    if (blockIdx.x < NBLK) {
        __shared__ int lcur[NBUCKET];
        for (int i = threadIdx.x; i < NBUCKET; i += 256)
            lcur[i] = offs[blockIdx.x * NBUCKET + i];
        __syncthreads();
        int base = blockIdx.x * EPB;
        int end = min(base + EPB, E);
        for (int i = base + threadIdx.x; i < end; i += 256) {
            int d = dst[i];
            int pos = atomicAdd(&lcur[d >> 8], 1);
            bedge[pos] = ((unsigned int)(d & 255) << 16) | (unsigned int)src[i];
            atomicAdd(&deg[d], 1);
        }
        return;
    }
    int g = (blockIdx.x - NBLK) * 2 + (threadIdx.x >> 7) + gofs;
    dual_tile_f32(x, Wl, Wr, bias, T, R, N, g);
}

// -- CSR step 4 (bucket build, single pass via deg[]) + layer-0 GEMM chunk ---
__global__ __launch_bounds__(256) void bucket_gemm_kernel(
        const unsigned int* __restrict__ bedge, const int* __restrict__ boff,
        const int* __restrict__ deg,
        int* __restrict__ row_ptr, float* __restrict__ inv_deg,
        int* __restrict__ col, int n,
        const float* __restrict__ x, const _Float16* __restrict__ Wl,
        const _Float16* __restrict__ Wr, const float* __restrict__ bias,
        _Float16* __restrict__ T, _Float16* __restrict__ R, int gofs) {
    if (blockIdx.x < NBUCKET) {
        __shared__ int sscan[256];
        __shared__ int lcur[256];
        const int b = blockIdx.x;
        const int t = threadIdx.x;
        const int base = boff[b];
        const int bend = boff[b + 1];
        const int node = b * 256 + t;
        const int d = (node < n) ? deg[node] : 0;
        sscan[t] = d;
        __syncthreads();
        for (int off = 1; off < 256; off <<= 1) {
            int tmp = (t >= off) ? sscan[t - off] : 0;
            __syncthreads();
            sscan[t] += tmp;
            __syncthreads();
        }
        int excl = sscan[t] - d;
        if (node < n) {
            row_ptr[node] = base + excl;
            inv_deg[node] = 1.0f / (float)max(d, 1);
        }
        lcur[t] = excl;
        __syncthreads();
        for (int i = base + t; i < bend; i += 256) {
            unsigned int v = bedge[i];
            int pos = atomicAdd(&lcur[v >> 16], 1);
            col[base + pos] = (int)(v & 0xffffu);
        }
        return;
    }
    int g = (blockIdx.x - NBUCKET) * 2 + (threadIdx.x >> 7) + gofs;
    dual_tile_f32(x, Wl, Wr, bias, T, R, n, g);
}

// ---------------- layer-0 finish: h1 = relu(R0 + inv_deg * sum T0[nbrs]) ----
// Gather structure identical to R10's proven aggregate (quarter-wave,
// 16 lanes x half8, 4 rows in flight, uniform bounds, full-wave shfl).
__global__ __launch_bounds__(128, 8) void agg_relu_kernel(
        const _Float16* __restrict__ T, const _Float16* __restrict__ R,
        const int* __restrict__ row_ptr, const int* __restrict__ col,
        const float* __restrict__ inv_deg, _Float16* __restrict__ h, int n) {
    int wave = threadIdx.x >> 6;
    int lane = threadIdx.x & 63;
    int node = blockIdx.x * 2 + wave;
    if (node >= n) return;
    int beg = row_ptr[node];
    int end = row_ptr[node + 1];
    const int quarter = lane >> 4;
    const int off = (lane & 15) << 3;     // half8 slice: 16 lanes x 8 halves = 128
    float a0f = 0.f, a1f = 0.f, a2f = 0.f, a3f = 0.f;
    float a4f = 0.f, a5f = 0.f, a6f = 0.f, a7f = 0.f;
    for (int base = beg; base < end; base += 64) {
        int m = end - base;
        if (m > 64) m = 64;
        int myc = (lane < m) ? col[base + lane] : 0;
        int t = 0;
        for (; t + 4 <= (m >> 2); t += 4) {
            int u0 = __shfl(myc, ((t + 0) << 2) + quarter);
            int u1 = __shfl(myc, ((t + 1) << 2) + quarter);
            int u2 = __shfl(myc, ((t + 2) << 2) + quarter);
            int u3 = __shfl(myc, ((t + 3) << 2) + quarter);
            half8 v0 = *(const half8*)&T[(size_t)u0 * D_H + off];
            half8 v1 = *(const half8*)&T[(size_t)u1 * D_H + off];
            half8 v2 = *(const half8*)&T[(size_t)u2 * D_H + off];
            half8 v3 = *(const half8*)&T[(size_t)u3 * D_H + off];
            a0f += (float)v0[0] + (float)v1[0] + (float)v2[0] + (float)v3[0];
            a1f += (float)v0[1] + (float)v1[1] + (float)v2[1] + (float)v3[1];
            a2f += (float)v0[2] + (float)v1[2] + (float)v2[2] + (float)v3[2];
            a3f += (float)v0[3] + (float)v1[3] + (float)v2[3] + (float)v3[3];
            a4f += (float)v0[4] + (float)v1[4] + (float)v2[4] + (float)v3[4];
            a5f += (float)v0[5] + (float)v1[5] + (float)v2[5] + (float)v3[5];
            a6f += (float)v0[6] + (float)v1[6] + (float)v2[6] + (float)v3[6];
            a7f += (float)v0[7] + (float)v1[7] + (float)v2[7] + (float)v3[7];
        }
        int smax = (m + 3) >> 2;
        for (; t < smax; ++t) {
            int j = (t << 2) + quarter;
            int u = __shfl(myc, j);
            if (j < m) {
                half8 v = *(const half8*)&T[(size_t)u * D_H + off];
                a0f += (float)v[0]; a1f += (float)v[1];
                a2f += (float)v[2]; a3f += (float)v[3];
                a4f += (float)v[4]; a5f += (float)v[5];
                a6f += (float)v[6]; a7f += (float)v[7];
            }
        }
    }
    a0f += __shfl(a0f, lane + 16); a1f += __shfl(a1f, lane + 16);
    a2f += __shfl(a2f, lane + 16); a3f += __shfl(a3f, lane + 16);
    a4f += __shfl(a4f, lane + 16); a5f += __shfl(a5f, lane + 16);
    a6f += __shfl(a6f, lane + 16); a7f += __shfl(a7f, lane + 16);
    a0f += __shfl(a0f, lane + 32); a1f += __shfl(a1f, lane + 32);
    a2f += __shfl(a2f, lane + 32); a3f += __shfl(a3f, lane + 32);
    a4f += __shfl(a4f, lane + 32); a5f += __shfl(a5f, lane + 32);
    a6f += __shfl(a6f, lane + 32); a7f += __shfl(a7f, lane + 32);
    if (quarter == 0) {
        float s = inv_deg[node];
        half8 r = *(const half8*)&R[(size_t)node * D_H + off];
        half8 o = { (_Float16)fmaxf((float)r[0] + a0f * s, 0.f),
                    (_Float16)fmaxf((float)r[1] + a1f * s, 0.f),
                    (_Float16)fmaxf((float)r[2] + a2f * s, 0.f),
                    (_Float16)fmaxf((float)r[3] + a3f * s, 0.f),
                    (_Float16)fmaxf((float)r[4] + a4f * s, 0.f),
                    (_Float16)fmaxf((float)r[5] + a5f * s, 0.f),
                    (_Float16)fmaxf((float)r[6] + a6f * s, 0.f),
                    (_Float16)fmaxf((float)r[7] + a7f * s, 0.f) };
        *(half8*)&h[(size_t)node * D_H + off] = o;
    }
}

// ---------------- plain aggregate: mean of neighbor rows (128-dim) ----------
// R10's proven kernel, unchanged: feeds the fused layer-1/2 GEMM.
__global__ __launch_bounds__(128, 8) void aggregate_kernel(const _Float16* __restrict__ h,
                                                           const int* __restrict__ row_ptr,
                                                           const int* __restrict__ col,
                                                           const float* __restrict__ inv_deg,
                                                           _Float16* __restrict__ agg, int n) {
    int wave = threadIdx.x >> 6;
    int lane = threadIdx.x & 63;
    int node = blockIdx.x * 2 + wave;
    if (node >= n) return;
    int beg = row_ptr[node];
    int end = row_ptr[node + 1];
    const int quarter = lane >> 4;
    const int off = (lane & 15) << 3;
    float a0f = 0.f, a1f = 0.f, a2f = 0.f, a3f = 0.f;
    float a4f = 0.f, a5f = 0.f, a6f = 0.f, a7f = 0.f;
    for (int base = beg; base < end; base += 64) {
        int m = end - base;
        if (m > 64) m = 64;
        int myc = (lane < m) ? col[base + lane] : 0;
        int t = 0;
        for (; t + 4 <= (m >> 2); t += 4) {
            int u0 = __shfl(myc, ((t + 0) << 2) + quarter);
            int u1 = __shfl(myc, ((t + 1) << 2) + quarter);
            int u2 = __shfl(myc, ((t + 2) << 2) + quarter);
            int u3 = __shfl(myc, ((t + 3) << 2) + quarter);
            half8 v0 = *(const half8*)&h[(size_t)u0 * D_H + off];
            half8 v1 = *(const half8*)&h[(size_t)u1 * D_H + off];
            half8 v2 = *(const half8*)&h[(size_t)u2 * D_H + off];
            half8 v3 = *(const half8*)&h[(size_t)u3 * D_H + off];
            a0f += (float)v0[0] + (float)v1[0] + (float)v2[0] + (float)v3[0];
            a1f += (float)v0[1] + (float)v1[1] + (float)v2[1] + (float)v3[1];
            a2f += (float)v0[2] + (float)v1[2] + (float)v2[2] + (float)v3[2];
            a3f += (float)v0[3] + (float)v1[3] + (float)v2[3] + (float)v3[3];
            a4f += (float)v0[4] + (float)v1[4] + (float)v2[4] + (float)v3[4];
            a5f += (float)v0[5] + (float)v1[5] + (float)v2[5] + (float)v3[5];
            a6f += (float)v0[6] + (float)v1[6] + (float)v2[6] + (float)v3[6];
            a7f += (float)v0[7] + (float)v1[7] + (float)v2[7] + (float)v3[7];
        }
        int smax = (m + 3) >> 2;
        for (; t < smax; ++t) {
            int j = (t << 2) + quarter;
            int u = __shfl(myc, j);
            if (j < m) {
                half8 v = *(const half8*)&h[(size_t)u * D_H + off];
                a0f += (float)v[0]; a1f += (float)v[1];
                a2f += (float)v[2]; a3f += (float)v[3];
                a4f += (float)v[4]; a5f += (float)v[5];
                a6f += (float)v[6]; a7f += (float)v[7];
            }
        }
    }
    a0f += __shfl(a0f, lane + 16); a1f += __shfl(a1f, lane + 16);
    a2f += __shfl(a2f, lane + 16); a3f += __shfl(a3f, lane + 16);
    a4f += __shfl(a4f, lane + 16); a5f += __shfl(a5f, lane + 16);
    a6f += __shfl(a6f, lane + 16); a7f += __shfl(a7f, lane + 16);
    a0f += __shfl(a0f, lane + 32); a1f += __shfl(a1f, lane + 32);
    a2f += __shfl(a2f, lane + 32); a3f += __shfl(a3f, lane + 32);
    a4f += __shfl(a4f, lane + 32); a5f += __shfl(a5f, lane + 32);
    a6f += __shfl(a6f, lane + 32); a7f += __shfl(a7f, lane + 32);
    if (quarter == 0) {
        float s = inv_deg[node];
        half8 o = { (_Float16)(a0f * s), (_Float16)(a1f * s),
                    (_Float16)(a2f * s), (_Float16)(a3f * s),
                    (_Float16)(a4f * s), (_Float16)(a5f * s),
                    (_Float16)(a6f * s), (_Float16)(a7f * s) };
        *(half8*)&agg[(size_t)node * D_H + off] = o;
    }
}

// ---- fused layer-1 finish + layer-2 dual GEMM (LDS hand-off, no h2 in HBM) --
// Phase 1 (== R14 gemm_mfma<8,true>): h2 = relu(agg1@Wl1^T + b1 + h1@Wr1^T),
//   64x128 fp16 tile -> LDS (stride 136 halves = 272B, 16B-aligned).
// Phase 2 (== R14 gemm_dual): T2 = h2@Wl2^T, Rh2 = h2@Wr2^T + b2, from LDS.
// Each wave reads only the 32 LDS rows it wrote; barrier kept for safety.
__global__ __launch_bounds__(128) void fused_l1l2_kernel(
        const _Float16* __restrict__ Xa, const _Float16* __restrict__ Xh,
        const _Float16* __restrict__ Wa, const _Float16* __restrict__ Wh,
        const float* __restrict__ b1,
        const _Float16* __restrict__ Wl2, const _Float16* __restrict__ Wr2,
        const float* __restrict__ b2,
        _Float16* __restrict__ T2, _Float16* __restrict__ Rh2, int N) {
    __shared__ _Float16 hs[64][136];     // 17.4 KB; +8 pad breaks bank alias
    const int wave = threadIdx.x >> 6;
    const int lane = threadIdx.x & 63;
    const int r16 = lane & 15;
    const int quad = lane >> 4;
    const int base = blockIdx.x * 64 + wave * 32;
    const int koff = quad * 8;

    // ---- phase 1: fused L1 GEMM into LDS ----
    {
        floatx4 acc[2][8];
        #pragma unroll
        for (int s = 0; s < 2; ++s)
            #pragma unroll
            for (int j = 0; j < 8; ++j)
                acc[s][j] = (floatx4){0.f, 0.f, 0.f, 0.f};

        #pragma unroll
        for (int hsel = 0; hsel < 2; ++hsel) {
            const _Float16* __restrict__ X = hsel ? Xh : Xa;
            const _Float16* __restrict__ W = hsel ? Wh : Wa;
            #pragma unroll
            for (int k0 = 0; k0 < 128; k0 += 32) {
                half8 a0 = *(const half8*)&X[(size_t)(base + r16) * 128 + k0 + koff];
                half8 a1 = *(const half8*)&X[(size_t)(base + 16 + r16) * 128 + k0 + koff];
                #pragma unroll
                for (int j = 0; j < 8; ++j) {
                    half8 b = *(const half8*)&W[(size_t)(j * 16 + r16) * 128 + k0 + koff];
                    acc[0][j] = __builtin_amdgcn_mfma_f32_16x16x32_f16(a0, b, acc[0][j], 0, 0, 0);
                    acc[1][j] = __builtin_amdgcn_mfma_f32_16x16x32_f16(a1, b, acc[1][j], 0, 0, 0);
                }
            }
        }

        #pragma unroll
        for (int s = 0; s < 2; ++s)
            #pragma unroll
            for (int i = 0; i < 4; ++i) {
                int lr = wave * 32 + s * 16 + quad * 4 + i;   // local row 0..63
                #pragma unroll
                for (int j = 0; j < 8; ++j) {
                    int c = j * 16 + r16;
                    hs[lr][c] = (_Float16)fmaxf(acc[s][j][i] + b1[c], 0.f);
                }
            }
    }
    __syncthreads();

    // ---- phase 2: dual L2 GEMM from LDS ----
    floatx4 accT[2][4], accR[2][4];
    #pragma unroll
    for (int s = 0; s < 2; ++s)
        #pragma unroll
        for (int j = 0; j < 4; ++j) {
            accT[s][j] = (floatx4){0.f, 0.f, 0.f, 0.f};
            accR[s][j] = (floatx4){0.f, 0.f, 0.f, 0.f};
        }

    #pragma unroll
    for (int k0 = 0; k0 < 128; k0 += 32) {
        half8 a0 = *(const half8*)&hs[wave * 32 + r16][k0 + koff];
        half8 a1 = *(const half8*)&hs[wave * 32 + 16 + r16][k0 + koff];
        #pragma unroll
        for (int j = 0; j < 4; ++j) {
            half8 bl = *(const half8*)&Wl2[(size_t)(j * 16 + r16) * 128 + k0 + koff];
            half8 br = *(const half8*)&Wr2[(size_t)(j * 16 + r16) * 128 + k0 + koff];
            accT[0][j] = __builtin_amdgcn_mfma_f32_16x16x32_f16(a0, bl, accT[0][j], 0, 0, 0);
            accT[1][j] = __builtin_amdgcn_mfma_f32_16x16x32_f16(a1, bl, accT[1][j], 0, 0, 0);
            accR[0][j] = __builtin_amdgcn_mfma_f32_16x16x32_f16(a0, br, accR[0][j], 0, 0, 0);
            accR[1][j] = __builtin_amdgcn_mfma_f32_16x16x32_f16(a1, br, accR[1][j], 0, 0, 0);
        }
    }

    #pragma unroll
    for (int s = 0; s < 2; ++s) {
        #pragma unroll
        for (int i = 0; i < 4; ++i) {
            int r = base + s * 16 + quad * 4 + i;
            if (r >= N) continue;
            #pragma unroll
            for (int j = 0; j < 4; ++j) {
                int c = j * 16 + r16;
                T2[(size_t)r * 64 + c]  = (_Float16)accT[s][j][i];
                Rh2[(size_t)r * 64 + c] = (_Float16)(accR[s][j][i] + b2[c]);
            }
        }
    }
}

// ---------------- layer-2 finish: out = Rh + inv_deg * sum T[neighbors] -----
__global__ __launch_bounds__(128, 8) void aggregate_add64_kernel(
        const _Float16* __restrict__ T,
        const _Float16* __restrict__ Rh,
        const int* __restrict__ row_ptr,
        const int* __restrict__ col,
        const float* __restrict__ inv_deg,
        float* __restrict__ out, int n) {
    int wave = threadIdx.x >> 6;
    int lane = threadIdx.x & 63;
    int node = blockIdx.x * 2 + wave;
    if (node >= n) return;
    int beg = row_ptr[node];
    int end = row_ptr[node + 1];
    const int quarter = lane >> 4;
    const int off = (lane & 15) << 2;     // half4 slice: 16 lanes x 4 halves = 64
    float a0f = 0.f, a1f = 0.f, a2f = 0.f, a3f = 0.f;
    for (int base = beg; base < end; base += 64) {
        int m = end - base;
        if (m > 64) m = 64;
        int myc = (lane < m) ? col[base + lane] : 0;
        int t = 0;
        for (; t + 4 <= (m >> 2); t += 4) {
            int u0 = __shfl(myc, ((t + 0) << 2) + quarter);
            int u1 = __shfl(myc, ((t + 1) << 2) + quarter);
            int u2 = __shfl(myc, ((t + 2) << 2) + quarter);
            int u3 = __shfl(myc, ((t + 3) << 2) + quarter);
            half4v v0 = *(const half4v*)&T[(size_t)u0 * 64 + off];
            half4v v1 = *(const half4v*)&T[(size_t)u1 * 64 + off];
            half4v v2 = *(const half4v*)&T[(size_t)u2 * 64 + off];
            half4v v3 = *(const half4v*)&T[(size_t)u3 * 64 + off];
            a0f += (float)v0[0] + (float)v1[0] + (float)v2[0] + (float)v3[0];
            a1f += (float)v0[1] + (float)v1[1] + (float)v2[1] + (float)v3[1];
            a2f += (float)v0[2] + (float)v1[2] + (float)v2[2] + (float)v3[2];
            a3f += (float)v0[3] + (float)v1[3] + (float)v2[3] + (float)v3[3];
        }
        int smax = (m + 3) >> 2;
        for (; t < smax; ++t) {
            int j = (t << 2) + quarter;
            int u = __shfl(myc, j);
            if (j < m) {
                half4v v = *(const half4v*)&T[(size_t)u * 64 + off];
                a0f += (float)v[0]; a1f += (float)v[1];
                a2f += (float)v[2]; a3f += (float)v[3];
            }
        }
    }
    a0f += __shfl(a0f, lane + 16); a1f += __shfl(a1f, lane + 16);
    a2f += __shfl(a2f, lane + 16); a3f += __shfl(a3f, lane + 16);
    a0f += __shfl(a0f, lane + 32); a1f += __shfl(a1f, lane + 32);
    a2f += __shfl(a2f, lane + 32); a3f += __shfl(a3f, lane + 32);
    if (quarter == 0) {
        float s = inv_deg[node];
        half4v r = *(const half4v*)&Rh[(size_t)node * 64 + off];
        float4 o;
        o.x = (float)r[0] + a0f * s;
        o.y = (float)r[1] + a1f * s;
        o.z = (float)r[2] + a2f * s;
        o.w = (float)r[3] + a3f * s;
        *(float4*)&out[(size_t)node * 64 + off] = o;
    }
}

extern "C" void kernel_launch(void* const* d_in, const int* in_sizes, int n_in,
                              void* d_out, int out_size, void* d_ws, size_t ws_size,
                              hipStream_t stream) {
    const float* x   = (const float*)d_in[0];
    const int*   edge = (const int*)d_in[1];   // int32: [2, E]
    const float* Wl0 = (const float*)d_in[2];
    const float* bl0 = (const float*)d_in[3];
    const float* Wr0 = (const float*)d_in[4];
    const float* Wl1 = (const float*)d_in[5];
    const float* bl1 = (const float*)d_in[6];
    const float* Wr1 = (const float*)d_in[7];
    const float* Wl2 = (const float*)d_in[8];
    const float* bl2 = (const float*)d_in[9];
    const float* Wr2 = (const float*)d_in[10];
    float* out = (float*)d_out;

    const int N = in_sizes[0] / D_H;   // 50000
    const int E = in_sizes[1] / 2;     // 800000
    const int* src = edge;
    const int* dst = edge + E;

    const int gx = (N + 63) / 64;      // 782 row-tiles of 64
    const int Np = gx * 64;
    const size_t HBYTES = (size_t)Np * D_H * 2;   // 12.8MB per fp16 node matrix

    // ---- workspace (~46MB), buffer lifetimes:
    //   Tb: T0 (CSR+GEMM) -> read agg_relu -> T2/Rh2 (fused_l1l2 out)
    //   Rb: R0 (CSR+GEMM) -> read agg_relu -> agg1 (aggregate out) -> read fused
    //   Hb: h1 (agg_relu out) -> read aggregate + fused
    char* w = (char*)d_ws;
    _Float16* Tb = (_Float16*)w;  w += HBYTES;
    _Float16* Rb = (_Float16*)w;  w += HBYTES;
    _Float16* Hb = (_Float16*)w;  w += HBYTES;
    _Float16* Wl0h = (_Float16*)w;  w += (size_t)128 * 128 * 2;
    _Float16* Wr0h = (_Float16*)w;  w += (size_t)128 * 128 * 2;
    _Float16* Wl1h = (_Float16*)w;  w += (size_t)128 * 128 * 2;
    _Float16* Wr1h = (_Float16*)w;  w += (size_t)128 * 128 * 2;
    _Float16* Wl2h = (_Float16*)w;  w += (size_t)64 * 128 * 2;
    _Float16* Wr2h = (_Float16*)w;  w += (size_t)64 * 128 * 2;
    int* row_ptr = (int*)w;      w += (size_t)(N + 16) * 4;
    float* inv_deg = (float*)w;  w += (size_t)N * 4;
    int* deg     = (int*)w;      w += (size_t)N * 4;
    int* col     = (int*)w;      w += (size_t)E * 4;
    int* histo   = (int*)w;      w += (size_t)NBLK * NBUCKET * 4;
    int* offs    = (int*)w;      w += (size_t)NBLK * NBUCKET * 4;
    int* boff    = (int*)w;      w += (size_t)(NBUCKET + 1) * 4;
    unsigned int* bedge = (unsigned int*)w;  w += (size_t)E * 4;

    _Float16* T2  = (_Float16*)Tb;                        // layer-2 T (6.4MB)
    _Float16* Rh2 = (_Float16*)((char*)Tb + HBYTES / 2);  // layer-2 Rh (6.4MB)

    // ---- CSR step 1 + weight conversions + deg zeroing (one dispatch) ----
    hist_wconv_kernel<<<NBLK + 80 + NZBLK, 256, 0, stream>>>(
        dst, histo, E,
        Wl0, Wr0, Wl1, Wr1, Wl2, Wr2,
        Wl0h, Wr0h, Wl1h, Wr1h, Wl2h, Wr2h,
        deg, N);

    // ---- CSR steps 2-4, each co-hosting a chunk of layer-0's dual GEMM ----
    // (T0 = x@Wl0^T, R0 = x@Wr0^T + bl0 -- independent of the CSR build).
    const int C0 = 260, C1 = 260, C2 = gx - C0 - C1;   // 262
    scan_gemm_kernel<<<1 + C0, 256, 0, stream>>>(
        histo, offs, boff, row_ptr, N,
        x, Wl0h, Wr0h, bl0, Tb, Rb, 0);
    scatter_gemm_kernel<<<NBLK + C1, 256, 0, stream>>>(
        src, dst, offs, bedge, deg, E,
        x, Wl0h, Wr0h, bl0, Tb, Rb, N, 2 * C0);
    bucket_gemm_kernel<<<NBUCKET + C2, 256, 0, stream>>>(
        bedge, boff, deg, row_ptr, inv_deg, col, N,
        x, Wl0h, Wr0h, bl0, Tb, Rb, 2 * (C0 + C1));

    const int agg_grid = (N + 1) / 2;     // 2 nodes per 128-thread block

    // ---- layer 0 finish: h1 = relu(R0 + mean T0[nbrs]) ----
    agg_relu_kernel<<<agg_grid, 128, 0, stream>>>(Tb, Rb, row_ptr, col, inv_deg, Hb, N);

    // ---- layer 1 gather: agg1 = mean h1[nbrs] ----
    aggregate_kernel<<<agg_grid, 128, 0, stream>>>(Hb, row_ptr, col, inv_deg, Rb, N);

    // ---- fused: h2 = relu(agg1@Wl1^T+b1+h1@Wr1^T) (LDS only);
    //      T2 = h2@Wl2^T, Rh2 = h2@Wr2^T + b2 ----
    fused_l1l2_kernel<<<gx, 128, 0, stream>>>(Rb, Hb, Wl1h, Wr1h, bl1,
                                              Wl2h, Wr2h, bl2, T2, Rh2, N);

    // ---- layer 2 finish: out = Rh2 + mean T2[nbrs] ----
    aggregate_add64_kernel<<<agg_grid, 128, 0, stream>>>(T2, Rh2, row_ptr, col,
                                                         inv_deg, out, N);
}

// Round 7
// 279.082 us; speedup vs baseline: 1.0776x; 1.0776x over previous
//
#include <hip/hip_runtime.h>

// ---------------------------------------------------------------------------
// FlexibleGraphSAGE: 3-layer SAGEConv (mean aggregation).
//   per layer: out = mean_agg(h) @ Wl^T + bl + h @ Wr^T   (+ReLU on layers 0,1)
// R19 == R16 resubmitted (R18 never ran: container failed twice; R16 measured
//   280.1us, passed, absmax 0.00390625 in Round 4).
// R17's deg-precompute REGRESSED (+20.6us): 800k random global atomicAdd in
//   scatter cost ~20us (scatter is outstanding-miss bound at 7% occupancy; any
//   added per-edge random access is paid in full on its critical path).
//   Ledger of neutral-or-worse vs this structure: R9 occupancy, R10 issue-rate,
//   R11 gather fusion, R13 L1 T-trick, R17 deg precompute.
// R16/R15: fused L1-finish/L2-dual GEMM (LDS hand-off, h2 never in HBM).
// R14: layer 0 = T-trick dual GEMM on f32 x co-scheduled inside CSR dispatches;
//   layer 1 fused (no R1 materialization); layer 2 T-trick (gather 128->64).
//   Gather kernels byte-identical to R10's proven quarter-wave structure
//   (pinned at random-256B fabric ceiling; all <44us per rocprof).
// ---------------------------------------------------------------------------

#define D_H 128
#define NBUCKET 196          // ceil(50000/256) node buckets of 256
#define EPB 8192             // edges per histogram/scatter block
#define NBLK 98              // ceil(800000/8192)

typedef _Float16 half8  __attribute__((ext_vector_type(8)));
typedef _Float16 half4v __attribute__((ext_vector_type(4)));
typedef float    floatx4 __attribute__((ext_vector_type(4)));

// ---------------- CSR step 1 + weight dtype conversion (merged) -------------
__global__ __launch_bounds__(256) void hist_wconv_kernel(
        const int* __restrict__ dst, int* __restrict__ histo, int E,
        const float* __restrict__ w0, const float* __restrict__ w1,
        const float* __restrict__ w2, const float* __restrict__ w3,
        const float* __restrict__ w4, const float* __restrict__ w5,
        _Float16* __restrict__ o0, _Float16* __restrict__ o1,
        _Float16* __restrict__ o2, _Float16* __restrict__ o3,
        _Float16* __restrict__ o4, _Float16* __restrict__ o5) {
    if (blockIdx.x < NBLK) {
        __shared__ int h[NBUCKET];
        for (int i = threadIdx.x; i < NBUCKET; i += 256) h[i] = 0;
        __syncthreads();
        int base = blockIdx.x * EPB;
        int end = min(base + EPB, E);
        for (int i = base + threadIdx.x; i < end; i += 256)
            atomicAdd(&h[dst[i] >> 8], 1);
        __syncthreads();
        for (int i = threadIdx.x; i < NBUCKET; i += 256)
            histo[blockIdx.x * NBUCKET + i] = h[i];
        return;
    }
    int k = (blockIdx.x - NBLK) * 256 + threadIdx.x;
    const float* in; _Float16* out; int j;
    if      (k <  4096) { in = w0; out = o0; j = k; }
    else if (k <  8192) { in = w1; out = o1; j = k - 4096; }
    else if (k < 12288) { in = w2; out = o2; j = k - 8192; }
    else if (k < 16384) { in = w3; out = o3; j = k - 12288; }
    else if (k < 18432) { in = w4; out = o4; j = k - 16384; }
    else if (k < 20480) { in = w5; out = o5; j = k - 18432; }
    else return;
    float4 v = ((const float4*)in)[j];
    half4v o = { (_Float16)v.x, (_Float16)v.y, (_Float16)v.z, (_Float16)v.w };
    ((half4v*)out)[j] = o;
}

// ---------------- dual GEMM tile (64 rows, T-pass or R-pass) ----------------
// gtile space: [0, ntile) = T-pass (out = A@Wl^T), [ntile, 2*ntile) = R-pass
// (out = A@Wr^T + bias). Two-pass keeps acc at 64 VGPRs; second x read is LLC.
__device__ __forceinline__ void dual_tile_f32(
        const float* __restrict__ Af,
        const _Float16* __restrict__ Wl, const _Float16* __restrict__ Wr,
        const float* __restrict__ bias,
        _Float16* __restrict__ T, _Float16* __restrict__ R,
        int N, int g) {
    const int ntile = (N + 63) >> 6;
    if (g >= 2 * ntile) return;
    const bool rpass = g >= ntile;
    const _Float16* __restrict__ W = rpass ? Wr : Wl;
    _Float16* __restrict__ O = rpass ? R : T;
    const int tile = rpass ? g - ntile : g;
    const int lt   = threadIdx.x & 127;
    const int wave = lt >> 6;
    const int lane = lt & 63;
    const int r16  = lane & 15;
    const int quad = lane >> 4;
    const int base = tile * 64 + wave * 32;
    const int koff = quad * 8;
    const int row0 = min(base + r16,      N - 1);   // clamp: x has exactly N rows
    const int row1 = min(base + 16 + r16, N - 1);

    floatx4 acc[2][8];
    #pragma unroll
    for (int s = 0; s < 2; ++s)
        #pragma unroll
        for (int j = 0; j < 8; ++j)
            acc[s][j] = (floatx4){0.f, 0.f, 0.f, 0.f};

    #pragma unroll
    for (int k0 = 0; k0 < 128; k0 += 32) {
        float4 p0 = *(const float4*)&Af[(size_t)row0 * 128 + k0 + koff];
        float4 p1 = *(const float4*)&Af[(size_t)row0 * 128 + k0 + koff + 4];
        float4 q0 = *(const float4*)&Af[(size_t)row1 * 128 + k0 + koff];
        float4 q1 = *(const float4*)&Af[(size_t)row1 * 128 + k0 + koff + 4];
        half8 a0 = (half8){ (_Float16)p0.x, (_Float16)p0.y, (_Float16)p0.z, (_Float16)p0.w,
                            (_Float16)p1.x, (_Float16)p1.y, (_Float16)p1.z, (_Float16)p1.w };
        half8 a1 = (half8){ (_Float16)q0.x, (_Float16)q0.y, (_Float16)q0.z, (_Float16)q0.w,
                            (_Float16)q1.x, (_Float16)q1.y, (_Float16)q1.z, (_Float16)q1.w };
        #pragma unroll
        for (int j = 0; j < 8; ++j) {
            half8 b = *(const half8*)&W[(size_t)(j * 16 + r16) * 128 + k0 + koff];
            acc[0][j] = __builtin_amdgcn_mfma_f32_16x16x32_f16(a0, b, acc[0][j], 0, 0, 0);
            acc[1][j] = __builtin_amdgcn_mfma_f32_16x16x32_f16(a1, b, acc[1][j], 0, 0, 0);
        }
    }

    #pragma unroll
    for (int s = 0; s < 2; ++s)
        #pragma unroll
        for (int i = 0; i < 4; ++i) {
            int r = base + s * 16 + quad * 4 + i;
            if (r >= N) continue;
            #pragma unroll
            for (int j = 0; j < 8; ++j) {
                int c = j * 16 + r16;
                float v = acc[s][j][i];
                if (rpass) v += bias[c];
                O[(size_t)r * 128 + c] = (_Float16)v;
            }
        }
}

// ---------------- CSR step 2 (scan) + layer-0 GEMM chunk --------------------
__global__ __launch_bounds__(256) void scan_gemm_kernel(
        const int* __restrict__ histo, int* __restrict__ offs,
        int* __restrict__ boff, int* __restrict__ row_ptr, int n,
        const float* __restrict__ x, const _Float16* __restrict__ Wl,
        const _Float16* __restrict__ Wr, const float* __restrict__ bias,
        _Float16* __restrict__ T, _Float16* __restrict__ R, int gofs) {
    if (blockIdx.x == 0) {
        __shared__ int s[256];
        int t = threadIdx.x;
        int sum = 0;
        if (t < NBUCKET) {
            for (int b = 0; b < NBLK; ++b) {
                offs[b * NBUCKET + t] = sum;
                sum += histo[b * NBUCKET + t];
            }
        }
        s[t] = (t < NBUCKET) ? sum : 0;
        int tot = s[t];
        __syncthreads();
        for (int off = 1; off < 256; off <<= 1) {
            int tmp = (t >= off) ? s[t - off] : 0;
            __syncthreads();
            s[t] += tmp;
            __syncthreads();
        }
        int base = s[t] - tot;
        if (t < NBUCKET) boff[t] = base;
        if (t == 255) { boff[NBUCKET] = s[255]; row_ptr[n] = s[255]; }
        __syncthreads();
        if (t < NBUCKET)
            for (int b = 0; b < NBLK; ++b)
                offs[b * NBUCKET + t] += base;
        return;
    }
    int g = (blockIdx.x - 1) * 2 + (threadIdx.x >> 7) + gofs;
    dual_tile_f32(x, Wl, Wr, bias, T, R, n, g);
}

// ---------------- CSR step 3 (scatter) + layer-0 GEMM chunk -----------------
__global__ __launch_bounds__(256) void scatter_gemm_kernel(
        const int* __restrict__ src, const int* __restrict__ dst,
        const int* __restrict__ offs, unsigned int* __restrict__ bedge, int E,
        const float* __restrict__ x, const _Float16* __restrict__ Wl,
        const _Float16* __restrict__ Wr, const float* __restrict__ bias,
        _Float16* __restrict__ T, _Float16* __restrict__ R, int N, int gofs) {
    if (blockIdx.x < NBLK) {
        __shared__ int lcur[NBUCKET];
        for (int i = threadIdx.x; i < NBUCKET; i += 256)
            lcur[i] = offs[blockIdx.x * NBUCKET + i];
        __syncthreads();
        int base = blockIdx.x * EPB;
        int end = min(base + EPB, E);
        for (int i = base + threadIdx.x; i < end; i += 256) {
            int d = dst[i];
            int pos = atomicAdd(&lcur[d >> 8], 1);
            bedge[pos] = ((unsigned int)(d & 255) << 16) | (unsigned int)src[i];
        }
        return;
    }
    int g = (blockIdx.x - NBLK) * 2 + (threadIdx.x >> 7) + gofs;
    dual_tile_f32(x, Wl, Wr, bias, T, R, N, g);
}

// ---------------- CSR step 4 (bucket build) + layer-0 GEMM chunk ------------
__global__ __launch_bounds__(256) void bucket_gemm_kernel(
        const unsigned int* __restrict__ bedge, const int* __restrict__ boff,
        int* __restrict__ row_ptr, float* __restrict__ inv_deg,
        int* __restrict__ col, int n,
        const float* __restrict__ x, const _Float16* __restrict__ Wl,
        const _Float16* __restrict__ Wr, const float* __restrict__ bias,
        _Float16* __restrict__ T, _Float16* __restrict__ R, int gofs) {
    if (blockIdx.x < NBUCKET) {
        __shared__ int sdeg[256];
        __shared__ int sscan[256];
        __shared__ int lcur[256];
        const int b = blockIdx.x;
        const int t = threadIdx.x;
        const int base = boff[b];
        const int bend = boff[b + 1];
        sdeg[t] = 0;
        __syncthreads();
        for (int i = base + t; i < bend; i += 256)
            atomicAdd(&sdeg[bedge[i] >> 16], 1);
        __syncthreads();
        int d = sdeg[t];
        sscan[t] = d;
        __syncthreads();
        for (int off = 1; off < 256; off <<= 1) {
            int tmp = (t >= off) ? sscan[t - off] : 0;
            __syncthreads();
            sscan[t] += tmp;
            __syncthreads();
        }
        int excl = sscan[t] - d;
        int node = b * 256 + t;
        if (node < n) {
            row_ptr[node] = base + excl;
            inv_deg[node] = 1.0f / (float)max(d, 1);
        }
        lcur[t] = excl;
        __syncthreads();
        for (int i = base + t; i < bend; i += 256) {
            unsigned int v = bedge[i];
            int pos = atomicAdd(&lcur[v >> 16], 1);
            col[base + pos] = (int)(v & 0xffffu);
        }
        return;
    }
    int g = (blockIdx.x - NBUCKET) * 2 + (threadIdx.x >> 7) + gofs;
    dual_tile_f32(x, Wl, Wr, bias, T, R, n, g);
}

// ---------------- layer-0 finish: h1 = relu(R0 + inv_deg * sum T0[nbrs]) ----
// Gather structure identical to R10's proven aggregate (quarter-wave,
// 16 lanes x half8, 4 rows in flight, uniform bounds, full-wave shfl).
__global__ __launch_bounds__(128, 8) void agg_relu_kernel(
        const _Float16* __restrict__ T, const _Float16* __restrict__ R,
        const int* __restrict__ row_ptr, const int* __restrict__ col,
        const float* __restrict__ inv_deg, _Float16* __restrict__ h, int n) {
    int wave = threadIdx.x >> 6;
    int lane = threadIdx.x & 63;
    int node = blockIdx.x * 2 + wave;
    if (node >= n) return;
    int beg = row_ptr[node];
    int end = row_ptr[node + 1];
    const int quarter = lane >> 4;
    const int off = (lane & 15) << 3;     // half8 slice: 16 lanes x 8 halves = 128
    float a0f = 0.f, a1f = 0.f, a2f = 0.f, a3f = 0.f;
    float a4f = 0.f, a5f = 0.f, a6f = 0.f, a7f = 0.f;
    for (int base = beg; base < end; base += 64) {
        int m = end - base;
        if (m > 64) m = 64;
        int myc = (lane < m) ? col[base + lane] : 0;
        int t = 0;
        for (; t + 4 <= (m >> 2); t += 4) {
            int u0 = __shfl(myc, ((t + 0) << 2) + quarter);
            int u1 = __shfl(myc, ((t + 1) << 2) + quarter);
            int u2 = __shfl(myc, ((t + 2) << 2) + quarter);
            int u3 = __shfl(myc, ((t + 3) << 2) + quarter);
            half8 v0 = *(const half8*)&T[(size_t)u0 * D_H + off];
            half8 v1 = *(const half8*)&T[(size_t)u1 * D_H + off];
            half8 v2 = *(const half8*)&T[(size_t)u2 * D_H + off];
            half8 v3 = *(const half8*)&T[(size_t)u3 * D_H + off];
            a0f += (float)v0[0] + (float)v1[0] + (float)v2[0] + (float)v3[0];
            a1f += (float)v0[1] + (float)v1[1] + (float)v2[1] + (float)v3[1];
            a2f += (float)v0[2] + (float)v1[2] + (float)v2[2] + (float)v3[2];
            a3f += (float)v0[3] + (float)v1[3] + (float)v2[3] + (float)v3[3];
            a4f += (float)v0[4] + (float)v1[4] + (float)v2[4] + (float)v3[4];
            a5f += (float)v0[5] + (float)v1[5] + (float)v2[5] + (float)v3[5];
            a6f += (float)v0[6] + (float)v1[6] + (float)v2[6] + (float)v3[6];
            a7f += (float)v0[7] + (float)v1[7] + (float)v2[7] + (float)v3[7];
        }
        int smax = (m + 3) >> 2;
        for (; t < smax; ++t) {
            int j = (t << 2) + quarter;
            int u = __shfl(myc, j);
            if (j < m) {
                half8 v = *(const half8*)&T[(size_t)u * D_H + off];
                a0f += (float)v[0]; a1f += (float)v[1];
                a2f += (float)v[2]; a3f += (float)v[3];
                a4f += (float)v[4]; a5f += (float)v[5];
                a6f += (float)v[6]; a7f += (float)v[7];
            }
        }
    }
    a0f += __shfl(a0f, lane + 16); a1f += __shfl(a1f, lane + 16);
    a2f += __shfl(a2f, lane + 16); a3f += __shfl(a3f, lane + 16);
    a4f += __shfl(a4f, lane + 16); a5f += __shfl(a5f, lane + 16);
    a6f += __shfl(a6f, lane + 16); a7f += __shfl(a7f, lane + 16);
    a0f += __shfl(a0f, lane + 32); a1f += __shfl(a1f, lane + 32);
    a2f += __shfl(a2f, lane + 32); a3f += __shfl(a3f, lane + 32);
    a4f += __shfl(a4f, lane + 32); a5f += __shfl(a5f, lane + 32);
    a6f += __shfl(a6f, lane + 32); a7f += __shfl(a7f, lane + 32);
    if (quarter == 0) {
        float s = inv_deg[node];
        half8 r = *(const half8*)&R[(size_t)node * D_H + off];
        half8 o = { (_Float16)fmaxf((float)r[0] + a0f * s, 0.f),
                    (_Float16)fmaxf((float)r[1] + a1f * s, 0.f),
                    (_Float16)fmaxf((float)r[2] + a2f * s, 0.f),
                    (_Float16)fmaxf((float)r[3] + a3f * s, 0.f),
                    (_Float16)fmaxf((float)r[4] + a4f * s, 0.f),
                    (_Float16)fmaxf((float)r[5] + a5f * s, 0.f),
                    (_Float16)fmaxf((float)r[6] + a6f * s, 0.f),
                    (_Float16)fmaxf((float)r[7] + a7f * s, 0.f) };
        *(half8*)&h[(size_t)node * D_H + off] = o;
    }
}

// ---------------- plain aggregate: mean of neighbor rows (128-dim) ----------
// R10's proven kernel, unchanged: feeds the fused layer-1/2 GEMM.
__global__ __launch_bounds__(128, 8) void aggregate_kernel(const _Float16* __restrict__ h,
                                                           const int* __restrict__ row_ptr,
                                                           const int* __restrict__ col,
                                                           const float* __restrict__ inv_deg,
                                                           _Float16* __restrict__ agg, int n) {
    int wave = threadIdx.x >> 6;
    int lane = threadIdx.x & 63;
    int node = blockIdx.x * 2 + wave;
    if (node >= n) return;
    int beg = row_ptr[node];
    int end = row_ptr[node + 1];
    const int quarter = lane >> 4;
    const int off = (lane & 15) << 3;
    float a0f = 0.f, a1f = 0.f, a2f = 0.f, a3f = 0.f;
    float a4f = 0.f, a5f = 0.f, a6f = 0.f, a7f = 0.f;
    for (int base = beg; base < end; base += 64) {
        int m = end - base;
        if (m > 64) m = 64;
        int myc = (lane < m) ? col[base + lane] : 0;
        int t = 0;
        for (; t + 4 <= (m >> 2); t += 4) {
            int u0 = __shfl(myc, ((t + 0) << 2) + quarter);
            int u1 = __shfl(myc, ((t + 1) << 2) + quarter);
            int u2 = __shfl(myc, ((t + 2) << 2) + quarter);
            int u3 = __shfl(myc, ((t + 3) << 2) + quarter);
            half8 v0 = *(const half8*)&h[(size_t)u0 * D_H + off];
            half8 v1 = *(const half8*)&h[(size_t)u1 * D_H + off];
            half8 v2 = *(const half8*)&h[(size_t)u2 * D_H + off];
            half8 v3 = *(const half8*)&h[(size_t)u3 * D_H + off];
            a0f += (float)v0[0] + (float)v1[0] + (float)v2[0] + (float)v3[0];
            a1f += (float)v0[1] + (float)v1[1] + (float)v2[1] + (float)v3[1];
            a2f += (float)v0[2] + (float)v1[2] + (float)v2[2] + (float)v3[2];
            a3f += (float)v0[3] + (float)v1[3] + (float)v2[3] + (float)v3[3];
            a4f += (float)v0[4] + (float)v1[4] + (float)v2[4] + (float)v3[4];
            a5f += (float)v0[5] + (float)v1[5] + (float)v2[5] + (float)v3[5];
            a6f += (float)v0[6] + (float)v1[6] + (float)v2[6] + (float)v3[6];
            a7f += (float)v0[7] + (float)v1[7] + (float)v2[7] + (float)v3[7];
        }
        int smax = (m + 3) >> 2;
        for (; t < smax; ++t) {
            int j = (t << 2) + quarter;
            int u = __shfl(myc, j);
            if (j < m) {
                half8 v = *(const half8*)&h[(size_t)u * D_H + off];
                a0f += (float)v[0]; a1f += (float)v[1];
                a2f += (float)v[2]; a3f += (float)v[3];
                a4f += (float)v[4]; a5f += (float)v[5];
                a6f += (float)v[6]; a7f += (float)v[7];
            }
        }
    }
    a0f += __shfl(a0f, lane + 16); a1f += __shfl(a1f, lane + 16);
    a2f += __shfl(a2f, lane + 16); a3f += __shfl(a3f, lane + 16);
    a4f += __shfl(a4f, lane + 16); a5f += __shfl(a5f, lane + 16);
    a6f += __shfl(a6f, lane + 16); a7f += __shfl(a7f, lane + 16);
    a0f += __shfl(a0f, lane + 32); a1f += __shfl(a1f, lane + 32);
    a2f += __shfl(a2f, lane + 32); a3f += __shfl(a3f, lane + 32);
    a4f += __shfl(a4f, lane + 32); a5f += __shfl(a5f, lane + 32);
    a6f += __shfl(a6f, lane + 32); a7f += __shfl(a7f, lane + 32);
    if (quarter == 0) {
        float s = inv_deg[node];
        half8 o = { (_Float16)(a0f * s), (_Float16)(a1f * s),
                    (_Float16)(a2f * s), (_Float16)(a3f * s),
                    (_Float16)(a4f * s), (_Float16)(a5f * s),
                    (_Float16)(a6f * s), (_Float16)(a7f * s) };
        *(half8*)&agg[(size_t)node * D_H + off] = o;
    }
}

// ---- fused layer-1 finish + layer-2 dual GEMM (LDS hand-off, no h2 in HBM) --
// Phase 1 (== R14 gemm_mfma<8,true>): h2 = relu(agg1@Wl1^T + b1 + h1@Wr1^T),
//   64x128 fp16 tile -> LDS (stride 136 halves = 272B, 16B-aligned).
// Phase 2 (== R14 gemm_dual): T2 = h2@Wl2^T, Rh2 = h2@Wr2^T + b2, from LDS.
// Each wave reads only the 32 LDS rows it wrote; barrier kept for safety.
__global__ __launch_bounds__(128) void fused_l1l2_kernel(
        const _Float16* __restrict__ Xa, const _Float16* __restrict__ Xh,
        const _Float16* __restrict__ Wa, const _Float16* __restrict__ Wh,
        const float* __restrict__ b1,
        const _Float16* __restrict__ Wl2, const _Float16* __restrict__ Wr2,
        const float* __restrict__ b2,
        _Float16* __restrict__ T2, _Float16* __restrict__ Rh2, int N) {
    __shared__ _Float16 hs[64][136];     // 17.4 KB; +8 pad breaks bank alias
    const int wave = threadIdx.x >> 6;
    const int lane = threadIdx.x & 63;
    const int r16 = lane & 15;
    const int quad = lane >> 4;
    const int base = blockIdx.x * 64 + wave * 32;
    const int koff = quad * 8;

    // ---- phase 1: fused L1 GEMM into LDS ----
    {
        floatx4 acc[2][8];
        #pragma unroll
        for (int s = 0; s < 2; ++s)
            #pragma unroll
            for (int j = 0; j < 8; ++j)
                acc[s][j] = (floatx4){0.f, 0.f, 0.f, 0.f};

        #pragma unroll
        for (int hsel = 0; hsel < 2; ++hsel) {
            const _Float16* __restrict__ X = hsel ? Xh : Xa;
            const _Float16* __restrict__ W = hsel ? Wh : Wa;
            #pragma unroll
            for (int k0 = 0; k0 < 128; k0 += 32) {
                half8 a0 = *(const half8*)&X[(size_t)(base + r16) * 128 + k0 + koff];
                half8 a1 = *(const half8*)&X[(size_t)(base + 16 + r16) * 128 + k0 + koff];
                #pragma unroll
                for (int j = 0; j < 8; ++j) {
                    half8 b = *(const half8*)&W[(size_t)(j * 16 + r16) * 128 + k0 + koff];
                    acc[0][j] = __builtin_amdgcn_mfma_f32_16x16x32_f16(a0, b, acc[0][j], 0, 0, 0);
                    acc[1][j] = __builtin_amdgcn_mfma_f32_16x16x32_f16(a1, b, acc[1][j], 0, 0, 0);
                }
            }
        }

        #pragma unroll
        for (int s = 0; s < 2; ++s)
            #pragma unroll
            for (int i = 0; i < 4; ++i) {
                int lr = wave * 32 + s * 16 + quad * 4 + i;   // local row 0..63
                #pragma unroll
                for (int j = 0; j < 8; ++j) {
                    int c = j * 16 + r16;
                    hs[lr][c] = (_Float16)fmaxf(acc[s][j][i] + b1[c], 0.f);
                }
            }
    }
    __syncthreads();

    // ---- phase 2: dual L2 GEMM from LDS ----
    floatx4 accT[2][4], accR[2][4];
    #pragma unroll
    for (int s = 0; s < 2; ++s)
        #pragma unroll
        for (int j = 0; j < 4; ++j) {
            accT[s][j] = (floatx4){0.f, 0.f, 0.f, 0.f};
            accR[s][j] = (floatx4){0.f, 0.f, 0.f, 0.f};
        }

    #pragma unroll
    for (int k0 = 0; k0 < 128; k0 += 32) {
        half8 a0 = *(const half8*)&hs[wave * 32 + r16][k0 + koff];
        half8 a1 = *(const half8*)&hs[wave * 32 + 16 + r16][k0 + koff];
        #pragma unroll
        for (int j = 0; j < 4; ++j) {
            half8 bl = *(const half8*)&Wl2[(size_t)(j * 16 + r16) * 128 + k0 + koff];
            half8 br = *(const half8*)&Wr2[(size_t)(j * 16 + r16) * 128 + k0 + koff];
            accT[0][j] = __builtin_amdgcn_mfma_f32_16x16x32_f16(a0, bl, accT[0][j], 0, 0, 0);
            accT[1][j] = __builtin_amdgcn_mfma_f32_16x16x32_f16(a1, bl, accT[1][j], 0, 0, 0);
            accR[0][j] = __builtin_amdgcn_mfma_f32_16x16x32_f16(a0, br, accR[0][j], 0, 0, 0);
            accR[1][j] = __builtin_amdgcn_mfma_f32_16x16x32_f16(a1, br, accR[1][j], 0, 0, 0);
        }
    }

    #pragma unroll
    for (int s = 0; s < 2; ++s) {
        #pragma unroll
        for (int i = 0; i < 4; ++i) {
            int r = base + s * 16 + quad * 4 + i;
            if (r >= N) continue;
            #pragma unroll
            for (int j = 0; j < 4; ++j) {
                int c = j * 16 + r16;
                T2[(size_t)r * 64 + c]  = (_Float16)accT[s][j][i];
                Rh2[(size_t)r * 64 + c] = (_Float16)(accR[s][j][i] + b2[c]);
            }
        }
    }
}

// ---------------- layer-2 finish: out = Rh + inv_deg * sum T[neighbors] -----
__global__ __launch_bounds__(128, 8) void aggregate_add64_kernel(
        const _Float16* __restrict__ T,
        const _Float16* __restrict__ Rh,
        const int* __restrict__ row_ptr,
        const int* __restrict__ col,
        const float* __restrict__ inv_deg,
        float* __restrict__ out, int n) {
    int wave = threadIdx.x >> 6;
    int lane = threadIdx.x & 63;
    int node = blockIdx.x * 2 + wave;
    if (node >= n) return;
    int beg = row_ptr[node];
    int end = row_ptr[node + 1];
    const int quarter = lane >> 4;
    const int off = (lane & 15) << 2;     // half4 slice: 16 lanes x 4 halves = 64
    float a0f = 0.f, a1f = 0.f, a2f = 0.f, a3f = 0.f;
    for (int base = beg; base < end; base += 64) {
        int m = end - base;
        if (m > 64) m = 64;
        int myc = (lane < m) ? col[base + lane] : 0;
        int t = 0;
        for (; t + 4 <= (m >> 2); t += 4) {
            int u0 = __shfl(myc, ((t + 0) << 2) + quarter);
            int u1 = __shfl(myc, ((t + 1) << 2) + quarter);
            int u2 = __shfl(myc, ((t + 2) << 2) + quarter);
            int u3 = __shfl(myc, ((t + 3) << 2) + quarter);
            half4v v0 = *(const half4v*)&T[(size_t)u0 * 64 + off];
            half4v v1 = *(const half4v*)&T[(size_t)u1 * 64 + off];
            half4v v2 = *(const half4v*)&T[(size_t)u2 * 64 + off];
            half4v v3 = *(const half4v*)&T[(size_t)u3 * 64 + off];
            a0f += (float)v0[0] + (float)v1[0] + (float)v2[0] + (float)v3[0];
            a1f += (float)v0[1] + (float)v1[1] + (float)v2[1] + (float)v3[1];
            a2f += (float)v0[2] + (float)v1[2] + (float)v2[2] + (float)v3[2];
            a3f += (float)v0[3] + (float)v1[3] + (float)v2[3] + (float)v3[3];
        }
        int smax = (m + 3) >> 2;
        for (; t < smax; ++t) {
            int j = (t << 2) + quarter;
            int u = __shfl(myc, j);
            if (j < m) {
                half4v v = *(const half4v*)&T[(size_t)u * 64 + off];
                a0f += (float)v[0]; a1f += (float)v[1];
                a2f += (float)v[2]; a3f += (float)v[3];
            }
        }
    }
    a0f += __shfl(a0f, lane + 16); a1f += __shfl(a1f, lane + 16);
    a2f += __shfl(a2f, lane + 16); a3f += __shfl(a3f, lane + 16);
    a0f += __shfl(a0f, lane + 32); a1f += __shfl(a1f, lane + 32);
    a2f += __shfl(a2f, lane + 32); a3f += __shfl(a3f, lane + 32);
    if (quarter == 0) {
        float s = inv_deg[node];
        half4v r = *(const half4v*)&Rh[(size_t)node * 64 + off];
        float4 o;
        o.x = (float)r[0] + a0f * s;
        o.y = (float)r[1] + a1f * s;
        o.z = (float)r[2] + a2f * s;
        o.w = (float)r[3] + a3f * s;
        *(float4*)&out[(size_t)node * 64 + off] = o;
    }
}

extern "C" void kernel_launch(void* const* d_in, const int* in_sizes, int n_in,
                              void* d_out, int out_size, void* d_ws, size_t ws_size,
                              hipStream_t stream) {
    const float* x   = (const float*)d_in[0];
    const int*   edge = (const int*)d_in[1];   // int32: [2, E]
    const float* Wl0 = (const float*)d_in[2];
    const float* bl0 = (const float*)d_in[3];
    const float* Wr0 = (const float*)d_in[4];
    const float* Wl1 = (const float*)d_in[5];
    const float* bl1 = (const float*)d_in[6];
    const float* Wr1 = (const float*)d_in[7];
    const float* Wl2 = (const float*)d_in[8];
    const float* bl2 = (const float*)d_in[9];
    const float* Wr2 = (const float*)d_in[10];
    float* out = (float*)d_out;

    const int N = in_sizes[0] / D_H;   // 50000
    const int E = in_sizes[1] / 2;     // 800000
    const int* src = edge;
    const int* dst = edge + E;

    const int gx = (N + 63) / 64;      // 782 row-tiles of 64
    const int Np = gx * 64;
    const size_t HBYTES = (size_t)Np * D_H * 2;   // 12.8MB per fp16 node matrix

    // ---- workspace (~46MB), buffer lifetimes:
    //   Tb: T0 (CSR+GEMM) -> read agg_relu -> T2/Rh2 (fused_l1l2 out)
    //   Rb: R0 (CSR+GEMM) -> read agg_relu -> agg1 (aggregate out) -> read fused
    //   Hb: h1 (agg_relu out) -> read aggregate + fused
    char* w = (char*)d_ws;
    _Float16* Tb = (_Float16*)w;  w += HBYTES;
    _Float16* Rb = (_Float16*)w;  w += HBYTES;
    _Float16* Hb = (_Float16*)w;  w += HBYTES;
    _Float16* Wl0h = (_Float16*)w;  w += (size_t)128 * 128 * 2;
    _Float16* Wr0h = (_Float16*)w;  w += (size_t)128 * 128 * 2;
    _Float16* Wl1h = (_Float16*)w;  w += (size_t)128 * 128 * 2;
    _Float16* Wr1h = (_Float16*)w;  w += (size_t)128 * 128 * 2;
    _Float16* Wl2h = (_Float16*)w;  w += (size_t)64 * 128 * 2;
    _Float16* Wr2h = (_Float16*)w;  w += (size_t)64 * 128 * 2;
    int* row_ptr = (int*)w;      w += (size_t)(N + 16) * 4;
    float* inv_deg = (float*)w;  w += (size_t)N * 4;
    int* col     = (int*)w;      w += (size_t)E * 4;
    int* histo   = (int*)w;      w += (size_t)NBLK * NBUCKET * 4;
    int* offs    = (int*)w;      w += (size_t)NBLK * NBUCKET * 4;
    int* boff    = (int*)w;      w += (size_t)(NBUCKET + 1) * 4;
    unsigned int* bedge = (unsigned int*)w;  w += (size_t)E * 4;

    _Float16* T2  = (_Float16*)Tb;                        // layer-2 T (6.4MB)
    _Float16* Rh2 = (_Float16*)((char*)Tb + HBYTES / 2);  // layer-2 Rh (6.4MB)

    // ---- CSR step 1 + weight conversions (one dispatch; x never converted) --
    hist_wconv_kernel<<<NBLK + 80, 256, 0, stream>>>(
        dst, histo, E,
        Wl0, Wr0, Wl1, Wr1, Wl2, Wr2,
        Wl0h, Wr0h, Wl1h, Wr1h, Wl2h, Wr2h);

    // ---- CSR steps 2-4, each co-hosting a chunk of layer-0's dual GEMM ----
    // (T0 = x@Wl0^T, R0 = x@Wr0^T + bl0 -- independent of the CSR build).
    const int C0 = 260, C1 = 260, C2 = gx - C0 - C1;   // 262
    scan_gemm_kernel<<<1 + C0, 256, 0, stream>>>(
        histo, offs, boff, row_ptr, N,
        x, Wl0h, Wr0h, bl0, Tb, Rb, 0);
    scatter_gemm_kernel<<<NBLK + C1, 256, 0, stream>>>(
        src, dst, offs, bedge, E,
        x, Wl0h, Wr0h, bl0, Tb, Rb, N, 2 * C0);
    bucket_gemm_kernel<<<NBUCKET + C2, 256, 0, stream>>>(
        bedge, boff, row_ptr, inv_deg, col, N,
        x, Wl0h, Wr0h, bl0, Tb, Rb, 2 * (C0 + C1));

    const int agg_grid = (N + 1) / 2;     // 2 nodes per 128-thread block

    // ---- layer 0 finish: h1 = relu(R0 + mean T0[nbrs]) ----
    agg_relu_kernel<<<agg_grid, 128, 0, stream>>>(Tb, Rb, row_ptr, col, inv_deg, Hb, N);

    // ---- layer 1 gather: agg1 = mean h1[nbrs] ----
    aggregate_kernel<<<agg_grid, 128, 0, stream>>>(Hb, row_ptr, col, inv_deg, Rb, N);

    // ---- fused: h2 = relu(agg1@Wl1^T+b1+h1@Wr1^T) (LDS only);
    //      T2 = h2@Wl2^T, Rh2 = h2@Wr2^T + b2 ----
    fused_l1l2_kernel<<<gx, 128, 0, stream>>>(Rb, Hb, Wl1h, Wr1h, bl1,
                                              Wl2h, Wr2h, bl2, T2, Rh2, N);

    // ---- layer 2 finish: out = Rh2 + mean T2[nbrs] ----
    aggregate_add64_kernel<<<agg_grid, 128, 0, stream>>>(T2, Rh2, row_ptr, col,
                                                         inv_deg, out, N);
}